// Round 1
// 1822.648 us; speedup vs baseline: 1.5682x; 1.5682x over previous
//
#include <hip/hip_runtime.h>

#define DEV __device__ __forceinline__

typedef unsigned short u16;
using bf16x8 = __attribute__((ext_vector_type(8))) __bf16;
using f32x4  = __attribute__((ext_vector_type(4))) float;

DEV u16 f2bf(float f){
  unsigned u = __float_as_uint(f);
  u += 0x7fffu + ((u >> 16) & 1u);   // round-to-nearest-even
  return (u16)(u >> 16);
}
DEV float sigf(float x){ return 1.f / (1.f + __expf(-x)); }
DEV float tanh_(float x){ return 2.f / (1.f + __expf(-2.f*x)) - 1.f; } // safe at +/-inf

DEV void async16(const u16* g, u16* l){
  __builtin_amdgcn_global_load_lds(
      (const __attribute__((address_space(1))) unsigned int*)g,
      (__attribute__((address_space(3))) unsigned int*)l, 16, 0, 0);
}

// ---------------- BatchNorm (training-mode batch stats, biased var) ----------
__global__ void bn_stats(const float* __restrict__ z, float* __restrict__ ps, float* __restrict__ pq){
  int bx = blockIdx.x; int rg = bx >> 2, cg = bx & 3;
  int c = cg*256 + threadIdx.x;
  float s = 0.f, q = 0.f;
  for (int r = rg*64; r < rg*64 + 64; ++r){ float v = z[r*1024 + c]; s += v; q += v*v; }
  ps[rg*1024 + c] = s; pq[rg*1024 + c] = q;
}

__global__ void bn_fin(const float* __restrict__ ps, const float* __restrict__ pq,
                       const float* __restrict__ gam, const float* __restrict__ bet,
                       float* __restrict__ sc, float* __restrict__ sh){
  int c = blockIdx.x*256 + threadIdx.x;
  float s = 0.f, q = 0.f;
  for (int rg = 0; rg < 16; ++rg){ s += ps[rg*1024 + c]; q += pq[rg*1024 + c]; }
  float mean = s * (1.f/1024.f);
  float var  = q * (1.f/1024.f) - mean*mean;
  float k = gam[c] * rsqrtf(var + 1e-5f);
  sc[c] = k; sh[c] = bet[c] - mean*k;
}

// zn -> h0 (bf16), h1 (bf16), c0 (f32), c1 (f32)
__global__ void bn_norm(const float* __restrict__ z, const float* __restrict__ sc, const float* __restrict__ sh,
                        u16* __restrict__ h0, u16* __restrict__ h1,
                        float* __restrict__ c0, float* __restrict__ c1){
  int bx = blockIdx.x; int rg = bx >> 2, cg = bx & 3;
  int c = cg*256 + threadIdx.x;
  float k = sc[c], b = sh[c];
  for (int r = rg*64; r < rg*64 + 64; ++r){
    float v = z[r*1024 + c]*k + b;
    u16 hv = f2bf(v);
    h0[r*1024 + c] = hv; h1[r*1024 + c] = hv;
    c0[r*1024 + c] = v;  c1[r*1024 + c] = v;
  }
}

// ---------------- weight convert (+gate-interleave permutation) --------------
__global__ void conv_w(const float* __restrict__ src, u16* __restrict__ dst,
                       int dstStride, int colOff, int permute){
  int c = blockIdx.x;
  int row = c;
  if (permute){ int gate = (c>>4)&3; int u = (c&15) | ((c>>6)<<4); row = (gate<<10) + u; }
  float4 v = ((const float4*)(src + (size_t)row*1024))[threadIdx.x];
  ushort4 o; o.x = f2bf(v.x); o.y = f2bf(v.y); o.z = f2bf(v.z); o.w = f2bf(v.w);
  ((ushort4*)(dst + (size_t)c*dstStride + colOff))[threadIdx.x] = o;
}

__global__ void bias_k(const float* __restrict__ bi0, const float* __restrict__ bh0,
                       const float* __restrict__ bi1, const float* __restrict__ bh1,
                       float* __restrict__ bx0, float* __restrict__ b1){
  int c = blockIdx.x*256 + threadIdx.x;           // 0..4095
  int gate = (c>>4)&3; int u = (c&15) | ((c>>6)<<4); int r = (gate<<10) + u;
  bx0[c] = bi0[r] + bh0[r];
  b1[c]  = bi1[r] + bh1[r];
}

// ---------------- GEMM core: C(128x128) = A(M,K) @ B(N,K)^T, bf16 MFMA ------
// Triple-buffered LDS, counted vmcnt, 1 barrier per K-step.
// LDS tile layout: row-major [128][32] u16, with 16B-slot swizzle:
//   LDS cell (row, slot) holds global k-slot = slot ^ ((row>>1)&3).
// Written via pre-swizzled GLOBAL source (global_load_lds dest stays linear),
// read back with the same XOR -> ds_read_b128 conflicts drop 8-way -> 2-way.
// MODE 0: store f32 gates+bias (x0 projection) to outf (ld 4096)
// MODE 1: LSTM layer-0 epilogue (add = x0proj matrix, incl. both biases)
// MODE 2: LSTM layer-1 epilogue (add = bias per col); also writes feats
// MODE 3: store f32 out + bias (ld 1024), unpermuted (linear head)
template<int MODE>
DEV void gemm_core(int bx, int by,
                   const u16* __restrict__ A0, const u16* __restrict__ A1, int KloA,
                   const u16* __restrict__ Bm, int K,
                   const float* __restrict__ add, float* __restrict__ cst,
                   u16* __restrict__ hout, u16* __restrict__ hout2,
                   float* __restrict__ outf,
                   u16* sA, u16* sB)                 // each 3*4096 u16
{
  const int t = threadIdx.x;
  const int lane = t & 63;
  const int w = t >> 6, wm = w >> 1, wn = w & 1;
  const int m0 = by*128, n0 = bx*128;

  f32x4 acc[4][4];
#pragma unroll
  for (int i = 0; i < 4; ++i)
#pragma unroll
    for (int j = 0; j < 4; ++j) acc[i][j] = (f32x4){0.f,0.f,0.f,0.f};

  const int rA = t >> 2;                         // staging row (q=0); q=1 adds 64
  // pre-swizzled source k-slot: slot (t&3) at row rA must hold global slot
  // (t&3) ^ f(row), f(row) = (row>>1)&3 = (t>>3)&3  (row+64 -> same f)
  const int kswz = (((t & 3) ^ ((t >> 3) & 3)) << 3);
  const int nkt = K >> 5;

  auto stage = [&](int kt, int b){
    const int k0 = kt << 5;
    const u16* aPart; int kk;
    if (k0 < KloA){ aPart = A0; kk = k0; } else { aPart = A1; kk = k0 - KloA; }
    u16* dA = sA + b*4096; u16* dB = sB + b*4096;
#pragma unroll
    for (int q = 0; q < 2; ++q){
      int row = rA + q*64;
      async16(aPart + (size_t)(m0 + row)*1024 + kk + kswz, dA + (t + q*256)*8);
      async16(Bm    + (size_t)(n0 + row)*K    + k0 + kswz, dB + (t + q*256)*8);
    }
  };

  // read-side swizzle: f(row) depends only on (lane>>1)&3 here (i*16, w*64 are %8==0 in row>>1 terms)
  const int rdswz = (((lane >> 4) ^ ((lane >> 1) & 3)) << 3);

  stage(0, 0);
  int cur = 0;
  for (int kt = 0; kt < nkt; ++kt){
    const int nxtb = (cur + 1 == 3) ? 0 : cur + 1;
    if (kt + 1 < nkt){
      stage(kt + 1, nxtb);
      asm volatile("s_waitcnt vmcnt(4)" ::: "memory");   // wait THIS tile's 4 loads; leave next 4 in flight
    } else {
      asm volatile("s_waitcnt vmcnt(0)" ::: "memory");
    }
    __builtin_amdgcn_sched_barrier(0);
    __builtin_amdgcn_s_barrier();                        // all waves' tile-kt loads landed
    __builtin_amdgcn_sched_barrier(0);

    const u16* pA = sA + cur*4096;
    const u16* pB = sB + cur*4096;
    bf16x8 af[4], bfr[4];
#pragma unroll
    for (int i = 0; i < 4; ++i){
      int ra = wm*64 + i*16 + (lane & 15);
      int rb = wn*64 + i*16 + (lane & 15);
      af[i]  = *(const bf16x8*)&pA[ra*32 + rdswz];
      bfr[i] = *(const bf16x8*)&pB[rb*32 + rdswz];
    }
#pragma unroll
    for (int i = 0; i < 4; ++i)
#pragma unroll
      for (int j = 0; j < 4; ++j)
        acc[i][j] = __builtin_amdgcn_mfma_f32_16x16x32_bf16(af[i], bfr[j], acc[i][j], 0, 0, 0);
    cur = nxtb;
    // no trailing barrier needed: stage(kt+2) targets the buffer read at kt-1,
    // separated from those reads by the barrier above (triple buffer).
  }

  const int s  = lane & 15;
  const int rq = (lane >> 4) * 4;

  if constexpr (MODE == 0 || MODE == 3){
    const int ldc = (MODE == 0) ? 4096 : 1024;
#pragma unroll
    for (int j = 0; j < 4; ++j){
      int col = n0 + wn*64 + j*16 + s;
      float bj = add[col];
#pragma unroll
      for (int i = 0; i < 4; ++i){
        int rowb = m0 + wm*64 + i*16 + rq;
#pragma unroll
        for (int r = 0; r < 4; ++r)
          outf[(size_t)(rowb + r)*ldc + col] = acc[i][j][r] + bj;
      }
    }
  } else {
    const int u = s + ((bx*2 + wn) << 4);     // hidden-unit index 0..1023
    int cidx[4]; float bj[4];
#pragma unroll
    for (int j = 0; j < 4; ++j){
      cidx[j] = n0 + wn*64 + j*16 + s;        // gate j lives at this col
      if (MODE == 2) bj[j] = add[cidx[j]];
    }
#pragma unroll
    for (int i = 0; i < 4; ++i){
      int rowb = m0 + wm*64 + i*16 + rq;
#pragma unroll
      for (int r = 0; r < 4; ++r){
        int row = rowb + r;
        float g0, g1, g2, g3;
        if (MODE == 1){
          const float* xp = add + (size_t)row*4096;
          g0 = acc[i][0][r] + xp[cidx[0]];
          g1 = acc[i][1][r] + xp[cidx[1]];
          g2 = acc[i][2][r] + xp[cidx[2]];
          g3 = acc[i][3][r] + xp[cidx[3]];
        } else {
          g0 = acc[i][0][r] + bj[0];
          g1 = acc[i][1][r] + bj[1];
          g2 = acc[i][2][r] + bj[2];
          g3 = acc[i][3][r] + bj[3];
        }
        float ig = sigf(g0), fg = sigf(g1), gg = tanh_(g2), og = sigf(g3);
        size_t si = (size_t)row*1024 + u;
        float cn = fg * cst[si] + ig * gg;
        cst[si] = cn;
        float hn = og * tanh_(cn);
        u16 hb = f2bf(hn);
        hout[si] = hb;
        if (MODE == 2) hout2[(size_t)row*32768 + u] = hb;  // feats[b][t][u]
      }
    }
  }
}

// ---- standalone GEMM (MODE 0 prep, MODE 3 head). SWZ: bijective XCD chunking
// so the 8 bx-blocks sharing one A-tile land on ONE XCD's L2 (grid (8,256)).
template<int MODE, int SWZ>
__global__ __launch_bounds__(256)
void gemm_k(const u16* __restrict__ A0, const u16* __restrict__ Bm, int K,
            const float* __restrict__ add, float* __restrict__ outf)
{
  __shared__ __align__(16) u16 sA[3*4096];
  __shared__ __align__(16) u16 sB[3*4096];
  int bx = blockIdx.x, by = blockIdx.y;
  if constexpr (SWZ){
    int lin = by * (int)gridDim.x + bx;   // hw: XCD = lin & 7
    int xcd = lin & 7, idx = lin >> 3;    // idx 0..255 within XCD
    by = xcd*32 + (idx >> 3);             // each XCD: 32 contiguous by-tiles
    bx = idx & 7;
  }
  gemm_core<MODE>(bx, by, A0, nullptr, 1<<20, Bm, K, add,
                  nullptr, nullptr, nullptr, outf, sA, sB);
}

// ---- fused step: L1(t) (blocks by<8) runs concurrently with L0(t+1) (by>=8).
// roles: 0 = both (grid y=16), 1 = L0 only (y=8), 2 = L1 only (y=8).
__global__ __launch_bounds__(256)
void fused_step(const u16* __restrict__ h0in, const u16* __restrict__ h1in,
                const u16* __restrict__ Whh0p, const u16* __restrict__ W1p,
                const float* __restrict__ X0p, const float* __restrict__ B1,
                float* __restrict__ C0, float* __restrict__ C1,
                u16* __restrict__ h0out, u16* __restrict__ h1out,
                u16* __restrict__ feats, int roles)
{
  __shared__ __align__(16) u16 sA[3*4096];
  __shared__ __align__(16) u16 sB[3*4096];
  int by = blockIdx.y, isL0;
  if (roles == 0){ isL0 = (by >= 8); by &= 7; }
  else isL0 = (roles == 1);
  if (isL0)   // h0(next) = cell(X0p, h0in, C0)
    gemm_core<1>(blockIdx.x, by, h0in, nullptr, 1<<20, Whh0p, 1024, X0p,
                 C0, h0out, nullptr, nullptr, sA, sB);
  else        // h1(next) = cell([h0in|h1in]@W1^T + B1, C1); writes feats
    gemm_core<2>(blockIdx.x, by, h0in, h1in, 1024, W1p, 2048, B1,
                 C1, h1out, feats, nullptr, sA, sB);
}

// ---------------------------------------------------------------------------
extern "C" void kernel_launch(void* const* d_in, const int* in_sizes, int n_in,
                              void* d_out, int out_size, void* d_ws, size_t ws_size,
                              hipStream_t stream)
{
  (void)in_sizes; (void)n_in; (void)out_size; (void)ws_size;
  const float* z    = (const float*)d_in[0];
  const float* gam  = (const float*)d_in[1];
  const float* bet  = (const float*)d_in[2];
  const float* Wih0 = (const float*)d_in[3];
  const float* Whh0 = (const float*)d_in[4];
  const float* bih0 = (const float*)d_in[5];
  const float* bhh0 = (const float*)d_in[6];
  const float* Wih1 = (const float*)d_in[7];
  const float* Whh1 = (const float*)d_in[8];
  const float* bih1 = (const float*)d_in[9];
  const float* bhh1 = (const float*)d_in[10];
  const float* Wlin = (const float*)d_in[11];
  const float* blin = (const float*)d_in[12];
  float* out = (float*)d_out;

  char* p = (char*)d_ws;
  auto alloc = [&](size_t b) -> void* { void* r = (void*)p; p += (b + 255) & ~(size_t)255; return r; };
  u16*  Wih0p = (u16*)alloc((size_t)4096*1024*2);
  u16*  Whh0p = (u16*)alloc((size_t)4096*1024*2);
  u16*  W1p   = (u16*)alloc((size_t)4096*2048*2);   // [W_ih1 | W_hh1] along K
  u16*  Wlinp = (u16*)alloc((size_t)1024*1024*2);
  float* Bx0  = (float*)alloc(4096*4);
  float* B1   = (float*)alloc(4096*4);
  float* X0p  = (float*)alloc((size_t)1024*4096*4);
  u16*  H0a   = (u16*)alloc((size_t)1024*1024*2);
  u16*  H0b   = (u16*)alloc((size_t)1024*1024*2);
  u16*  H1a   = (u16*)alloc((size_t)1024*1024*2);
  u16*  H1b   = (u16*)alloc((size_t)1024*1024*2);
  float* C0   = (float*)alloc((size_t)1024*1024*4);
  float* C1   = (float*)alloc((size_t)1024*1024*4);
  u16*  Feats = (u16*)alloc((size_t)1024*32*1024*2);
  float* PS   = (float*)alloc(16*1024*4);
  float* PQ   = (float*)alloc(16*1024*4);
  float* Sc   = (float*)alloc(1024*4);
  float* Sh   = (float*)alloc(1024*4);

  // prep
  bn_stats<<<64, 256, 0, stream>>>(z, PS, PQ);
  bn_fin<<<4, 256, 0, stream>>>(PS, PQ, gam, bet, Sc, Sh);
  bn_norm<<<64, 256, 0, stream>>>(z, Sc, Sh, H0a, H1a, C0, C1);
  conv_w<<<4096, 256, 0, stream>>>(Wih0, Wih0p, 1024, 0, 1);
  conv_w<<<4096, 256, 0, stream>>>(Whh0, Whh0p, 1024, 0, 1);
  conv_w<<<4096, 256, 0, stream>>>(Wih1, W1p, 2048, 0, 1);
  conv_w<<<4096, 256, 0, stream>>>(Whh1, W1p, 2048, 1024, 1);
  conv_w<<<1024, 256, 0, stream>>>(Wlin, Wlinp, 1024, 0, 0);
  bias_k<<<16, 256, 0, stream>>>(bih0, bhh0, bih1, bhh1, Bx0, B1);

  // x0_proj = zn @ W_ih0p^T + (b_ih0 + b_hh0)   (constant over steps)
  gemm_k<0,0><<<dim3(32,8), 256, 0, stream>>>(H0a, Wih0p, 1024, Bx0, X0p);

  u16* h0b[2] = {H0a, H0b};
  u16* h1b[2] = {H1a, H1b};

  // h0(1) <- h0(0): L0 alone (nothing to overlap with yet)
  fused_step<<<dim3(32,8), 256, 0, stream>>>(h0b[0], nullptr, Whh0p, W1p, X0p, B1,
                                             C0, C1, h0b[1], nullptr, nullptr, 1);
  // steps t=0..30: L1(t) uses h0(t+1); concurrently L0 computes h0(t+2)
  for (int t = 0; t < 31; ++t){
    fused_step<<<dim3(32,16), 256, 0, stream>>>(
        h0b[(t+1)&1], h1b[t&1], Whh0p, W1p, X0p, B1,
        C0, C1, h0b[t&1], h1b[(t+1)&1], Feats + (size_t)t*1024, 0);
  }
  // final L1(31): uses h0(32)=h0b[0], h1 state h1b[1]
  fused_step<<<dim3(32,8), 256, 0, stream>>>(h0b[0], h1b[1], Whh0p, W1p, X0p, B1,
                                             C0, C1, nullptr, h1b[0], Feats + (size_t)31*1024, 2);

  // out = feats @ W_lin^T + b_lin  (XCD-chunked swizzle for A-tile L2 reuse)
  gemm_k<3,1><<<dim3(8,256), 256, 0, stream>>>(Feats, Wlinp, 1024, blin, out);
}

// Round 2
// 1796.896 us; speedup vs baseline: 1.5907x; 1.0143x over previous
//
#include <hip/hip_runtime.h>

#define DEV __device__ __forceinline__

typedef unsigned short u16;
using bf16x8 = __attribute__((ext_vector_type(8))) __bf16;
using f32x4  = __attribute__((ext_vector_type(4))) float;

DEV u16 f2bf(float f){
  unsigned u = __float_as_uint(f);
  u += 0x7fffu + ((u >> 16) & 1u);   // round-to-nearest-even
  return (u16)(u >> 16);
}
DEV float sigf(float x){ return 1.f / (1.f + __expf(-x)); }
DEV float tanh_(float x){ return 2.f / (1.f + __expf(-2.f*x)) - 1.f; } // safe at +/-inf

DEV void async16(const u16* g, u16* l){
  __builtin_amdgcn_global_load_lds(
      (const __attribute__((address_space(1))) unsigned int*)g,
      (__attribute__((address_space(3))) unsigned int*)l, 16, 0, 0);
}

// ---------------- BatchNorm (training-mode batch stats, biased var) ----------
__global__ void bn_stats(const float* __restrict__ z, float* __restrict__ ps, float* __restrict__ pq){
  int bx = blockIdx.x; int rg = bx >> 2, cg = bx & 3;
  int c = cg*256 + threadIdx.x;
  float s = 0.f, q = 0.f;
  for (int r = rg*64; r < rg*64 + 64; ++r){ float v = z[r*1024 + c]; s += v; q += v*v; }
  ps[rg*1024 + c] = s; pq[rg*1024 + c] = q;
}

__global__ void bn_fin(const float* __restrict__ ps, const float* __restrict__ pq,
                       const float* __restrict__ gam, const float* __restrict__ bet,
                       float* __restrict__ sc, float* __restrict__ sh){
  int c = blockIdx.x*256 + threadIdx.x;
  float s = 0.f, q = 0.f;
  for (int rg = 0; rg < 16; ++rg){ s += ps[rg*1024 + c]; q += pq[rg*1024 + c]; }
  float mean = s * (1.f/1024.f);
  float var  = q * (1.f/1024.f) - mean*mean;
  float k = gam[c] * rsqrtf(var + 1e-5f);
  sc[c] = k; sh[c] = bet[c] - mean*k;
}

// zn -> h0 (bf16), h1 (bf16), c0 (f32), c1 (f32)
__global__ void bn_norm(const float* __restrict__ z, const float* __restrict__ sc, const float* __restrict__ sh,
                        u16* __restrict__ h0, u16* __restrict__ h1,
                        float* __restrict__ c0, float* __restrict__ c1){
  int bx = blockIdx.x; int rg = bx >> 2, cg = bx & 3;
  int c = cg*256 + threadIdx.x;
  float k = sc[c], b = sh[c];
  for (int r = rg*64; r < rg*64 + 64; ++r){
    float v = z[r*1024 + c]*k + b;
    u16 hv = f2bf(v);
    h0[r*1024 + c] = hv; h1[r*1024 + c] = hv;
    c0[r*1024 + c] = v;  c1[r*1024 + c] = v;
  }
}

// ---------------- weight convert (+gate-interleave permutation) --------------
__global__ void conv_w(const float* __restrict__ src, u16* __restrict__ dst,
                       int dstStride, int colOff, int permute){
  int c = blockIdx.x;
  int row = c;
  if (permute){ int gate = (c>>4)&3; int u = (c&15) | ((c>>6)<<4); row = (gate<<10) + u; }
  float4 v = ((const float4*)(src + (size_t)row*1024))[threadIdx.x];
  ushort4 o; o.x = f2bf(v.x); o.y = f2bf(v.y); o.z = f2bf(v.z); o.w = f2bf(v.w);
  ((ushort4*)(dst + (size_t)c*dstStride + colOff))[threadIdx.x] = o;
}

__global__ void bias_k(const float* __restrict__ bi0, const float* __restrict__ bh0,
                       const float* __restrict__ bi1, const float* __restrict__ bh1,
                       float* __restrict__ bx0, float* __restrict__ b1){
  int c = blockIdx.x*256 + threadIdx.x;           // 0..4095
  int gate = (c>>4)&3; int u = (c&15) | ((c>>6)<<4); int r = (gate<<10) + u;
  bx0[c] = bi0[r] + bh0[r];
  b1[c]  = bi1[r] + bh1[r];
}

// ---------------- GEMM core: C(128x128) = A(M,K) @ B(N,K)^T, bf16 MFMA ------
// 4-buffer LDS, depth-2 prefetch (2 tiles in flight), counted vmcnt(8),
// ONE barrier per K-step. Write-after-read safety: stage(k+2) writes
// b[(k-2)&3], whose reads (iter k-2) are separated from the write-issue by
// the iter-(k-1) barrier. s_setprio(1) wraps the MFMA cluster (T5).
// LDS tile layout: row-major [128][32] u16, with 16B-slot swizzle:
//   LDS cell (row, slot) holds global k-slot = slot ^ ((row>>1)&3).
// Written via pre-swizzled GLOBAL source (global_load_lds dest stays linear),
// read back with the same XOR -> ds_read_b128 conflicts 8-way -> 2-way (free).
// MODE 0: store f32 gates+bias (x0 projection) to outf (ld 4096)
// MODE 1: LSTM layer-0 epilogue (add = x0proj matrix, incl. both biases)
// MODE 2: LSTM layer-1 epilogue (add = bias per col); also writes feats
// MODE 3: store f32 out + bias (ld 1024), unpermuted (linear head)
template<int MODE>
DEV void gemm_core(int bx, int by,
                   const u16* __restrict__ A0, const u16* __restrict__ A1, int KloA,
                   const u16* __restrict__ Bm, int K,
                   const float* __restrict__ add, float* __restrict__ cst,
                   u16* __restrict__ hout, u16* __restrict__ hout2,
                   float* __restrict__ outf,
                   u16* sA, u16* sB)                 // each 4*4096 u16
{
  const int t = threadIdx.x;
  const int lane = t & 63;
  const int w = t >> 6, wm = w >> 1, wn = w & 1;
  const int m0 = by*128, n0 = bx*128;

  f32x4 acc[4][4];
#pragma unroll
  for (int i = 0; i < 4; ++i)
#pragma unroll
    for (int j = 0; j < 4; ++j) acc[i][j] = (f32x4){0.f,0.f,0.f,0.f};

  const int rA = t >> 2;                         // staging row (q=0); q=1 adds 64
  // pre-swizzled source k-slot: slot (t&3) at row rA must hold global slot
  // (t&3) ^ f(row), f(row) = (row>>1)&3 = (t>>3)&3  (row+64 -> same f)
  const int kswz = (((t & 3) ^ ((t >> 3) & 3)) << 3);
  const int nkt = K >> 5;

  auto stage = [&](int kt, int b){
    const int k0 = kt << 5;
    const u16* aPart; int kk;
    if (k0 < KloA){ aPart = A0; kk = k0; } else { aPart = A1; kk = k0 - KloA; }
    u16* dA = sA + b*4096; u16* dB = sB + b*4096;
#pragma unroll
    for (int q = 0; q < 2; ++q){
      int row = rA + q*64;
      async16(aPart + (size_t)(m0 + row)*1024 + kk + kswz, dA + (t + q*256)*8);
      async16(Bm    + (size_t)(n0 + row)*K    + k0 + kswz, dB + (t + q*256)*8);
    }
  };

  // read-side swizzle: f(row) depends only on (lane>>1)&3 here
  const int rdswz = (((lane >> 4) ^ ((lane >> 1) & 3)) << 3);

  stage(0, 0);
  stage(1, 1);
  for (int kt = 0; kt < nkt; ++kt){
    if (kt + 2 < nkt){
      stage(kt + 2, (kt + 2) & 3);
      asm volatile("s_waitcnt vmcnt(8)" ::: "memory");   // tiles k+1,k+2 in flight; tile k landed
    } else if (kt + 1 < nkt){
      asm volatile("s_waitcnt vmcnt(4)" ::: "memory");   // tile k+1 in flight
    } else {
      asm volatile("s_waitcnt vmcnt(0)" ::: "memory");
    }
    __builtin_amdgcn_sched_barrier(0);
    __builtin_amdgcn_s_barrier();                        // all waves' tile-kt loads landed
    __builtin_amdgcn_sched_barrier(0);

    const u16* pA = sA + (kt & 3)*4096;
    const u16* pB = sB + (kt & 3)*4096;
    bf16x8 af[4], bfr[4];
#pragma unroll
    for (int i = 0; i < 4; ++i){
      int ra = wm*64 + i*16 + (lane & 15);
      int rb = wn*64 + i*16 + (lane & 15);
      af[i]  = *(const bf16x8*)&pA[ra*32 + rdswz];
      bfr[i] = *(const bf16x8*)&pB[rb*32 + rdswz];
    }
    __builtin_amdgcn_s_setprio(1);
#pragma unroll
    for (int i = 0; i < 4; ++i)
#pragma unroll
      for (int j = 0; j < 4; ++j)
        acc[i][j] = __builtin_amdgcn_mfma_f32_16x16x32_bf16(af[i], bfr[j], acc[i][j], 0, 0, 0);
    __builtin_amdgcn_s_setprio(0);
    // no trailing barrier: NBUF=4 gives the slack (see header comment).
  }

  const int s  = lane & 15;
  const int rq = (lane >> 4) * 4;

  if constexpr (MODE == 0 || MODE == 3){
    const int ldc = (MODE == 0) ? 4096 : 1024;
#pragma unroll
    for (int j = 0; j < 4; ++j){
      int col = n0 + wn*64 + j*16 + s;
      float bj = add[col];
#pragma unroll
      for (int i = 0; i < 4; ++i){
        int rowb = m0 + wm*64 + i*16 + rq;
#pragma unroll
        for (int r = 0; r < 4; ++r)
          outf[(size_t)(rowb + r)*ldc + col] = acc[i][j][r] + bj;
      }
    }
  } else {
    const int u = s + ((bx*2 + wn) << 4);     // hidden-unit index 0..1023
    int cidx[4]; float bj[4];
#pragma unroll
    for (int j = 0; j < 4; ++j){
      cidx[j] = n0 + wn*64 + j*16 + s;        // gate j lives at this col
      if (MODE == 2) bj[j] = add[cidx[j]];
    }
#pragma unroll
    for (int i = 0; i < 4; ++i){
      int rowb = m0 + wm*64 + i*16 + rq;
#pragma unroll
      for (int r = 0; r < 4; ++r){
        int row = rowb + r;
        float g0, g1, g2, g3;
        if (MODE == 1){
          const float* xp = add + (size_t)row*4096;
          g0 = acc[i][0][r] + xp[cidx[0]];
          g1 = acc[i][1][r] + xp[cidx[1]];
          g2 = acc[i][2][r] + xp[cidx[2]];
          g3 = acc[i][3][r] + xp[cidx[3]];
        } else {
          g0 = acc[i][0][r] + bj[0];
          g1 = acc[i][1][r] + bj[1];
          g2 = acc[i][2][r] + bj[2];
          g3 = acc[i][3][r] + bj[3];
        }
        float ig = sigf(g0), fg = sigf(g1), gg = tanh_(g2), og = sigf(g3);
        size_t si = (size_t)row*1024 + u;
        float cn = fg * cst[si] + ig * gg;
        cst[si] = cn;
        float hn = og * tanh_(cn);
        u16 hb = f2bf(hn);
        hout[si] = hb;
        if (MODE == 2) hout2[(size_t)row*32768 + u] = hb;  // feats[b][t][u]
      }
    }
  }
}

// ---- standalone GEMM (MODE 0 prep, MODE 3 head). SWZ: bijective XCD chunking
// so the 8 bx-blocks sharing one A-tile land on ONE XCD's L2 (grid (8,256)).
template<int MODE, int SWZ>
__global__ __launch_bounds__(256)
void gemm_k(const u16* __restrict__ A0, const u16* __restrict__ Bm, int K,
            const float* __restrict__ add, float* __restrict__ outf)
{
  __shared__ __align__(16) u16 sA[4*4096];
  __shared__ __align__(16) u16 sB[4*4096];
  int bx = blockIdx.x, by = blockIdx.y;
  if constexpr (SWZ){
    int lin = by * (int)gridDim.x + bx;   // hw: XCD = lin & 7
    int xcd = lin & 7, idx = lin >> 3;    // idx 0..255 within XCD
    by = xcd*32 + (idx >> 3);             // each XCD: 32 contiguous by-tiles
    bx = idx & 7;
  }
  gemm_core<MODE>(bx, by, A0, nullptr, 1<<20, Bm, K, add,
                  nullptr, nullptr, nullptr, outf, sA, sB);
}

// ---- fused step: L1(t) (blocks by<8) runs concurrently with L0(t+1) (by>=8).
// roles: 0 = both (grid y=16), 1 = L0 only (y=8), 2 = L1 only (y=8).
__global__ __launch_bounds__(256)
void fused_step(const u16* __restrict__ h0in, const u16* __restrict__ h1in,
                const u16* __restrict__ Whh0p, const u16* __restrict__ W1p,
                const float* __restrict__ X0p, const float* __restrict__ B1,
                float* __restrict__ C0, float* __restrict__ C1,
                u16* __restrict__ h0out, u16* __restrict__ h1out,
                u16* __restrict__ feats, int roles)
{
  __shared__ __align__(16) u16 sA[4*4096];
  __shared__ __align__(16) u16 sB[4*4096];
  int by = blockIdx.y, isL0;
  if (roles == 0){ isL0 = (by >= 8); by &= 7; }
  else isL0 = (roles == 1);
  if (isL0)   // h0(next) = cell(X0p, h0in, C0)
    gemm_core<1>(blockIdx.x, by, h0in, nullptr, 1<<20, Whh0p, 1024, X0p,
                 C0, h0out, nullptr, nullptr, sA, sB);
  else        // h1(next) = cell([h0in|h1in]@W1^T + B1, C1); writes feats
    gemm_core<2>(blockIdx.x, by, h0in, h1in, 1024, W1p, 2048, B1,
                 C1, h1out, feats, nullptr, sA, sB);
}

// ---------------------------------------------------------------------------
extern "C" void kernel_launch(void* const* d_in, const int* in_sizes, int n_in,
                              void* d_out, int out_size, void* d_ws, size_t ws_size,
                              hipStream_t stream)
{
  (void)in_sizes; (void)n_in; (void)out_size; (void)ws_size;
  const float* z    = (const float*)d_in[0];
  const float* gam  = (const float*)d_in[1];
  const float* bet  = (const float*)d_in[2];
  const float* Wih0 = (const float*)d_in[3];
  const float* Whh0 = (const float*)d_in[4];
  const float* bih0 = (const float*)d_in[5];
  const float* bhh0 = (const float*)d_in[6];
  const float* Wih1 = (const float*)d_in[7];
  const float* Whh1 = (const float*)d_in[8];
  const float* bih1 = (const float*)d_in[9];
  const float* bhh1 = (const float*)d_in[10];
  const float* Wlin = (const float*)d_in[11];
  const float* blin = (const float*)d_in[12];
  float* out = (float*)d_out;

  char* p = (char*)d_ws;
  auto alloc = [&](size_t b) -> void* { void* r = (void*)p; p += (b + 255) & ~(size_t)255; return r; };
  u16*  Wih0p = (u16*)alloc((size_t)4096*1024*2);
  u16*  Whh0p = (u16*)alloc((size_t)4096*1024*2);
  u16*  W1p   = (u16*)alloc((size_t)4096*2048*2);   // [W_ih1 | W_hh1] along K
  u16*  Wlinp = (u16*)alloc((size_t)1024*1024*2);
  float* Bx0  = (float*)alloc(4096*4);
  float* B1   = (float*)alloc(4096*4);
  float* X0p  = (float*)alloc((size_t)1024*4096*4);
  u16*  H0a   = (u16*)alloc((size_t)1024*1024*2);
  u16*  H0b   = (u16*)alloc((size_t)1024*1024*2);
  u16*  H1a   = (u16*)alloc((size_t)1024*1024*2);
  u16*  H1b   = (u16*)alloc((size_t)1024*1024*2);
  float* C0   = (float*)alloc((size_t)1024*1024*4);
  float* C1   = (float*)alloc((size_t)1024*1024*4);
  u16*  Feats = (u16*)alloc((size_t)1024*32*1024*2);
  float* PS   = (float*)alloc(16*1024*4);
  float* PQ   = (float*)alloc(16*1024*4);
  float* Sc   = (float*)alloc(1024*4);
  float* Sh   = (float*)alloc(1024*4);

  // prep
  bn_stats<<<64, 256, 0, stream>>>(z, PS, PQ);
  bn_fin<<<4, 256, 0, stream>>>(PS, PQ, gam, bet, Sc, Sh);
  bn_norm<<<64, 256, 0, stream>>>(z, Sc, Sh, H0a, H1a, C0, C1);
  conv_w<<<4096, 256, 0, stream>>>(Wih0, Wih0p, 1024, 0, 1);
  conv_w<<<4096, 256, 0, stream>>>(Whh0, Whh0p, 1024, 0, 1);
  conv_w<<<4096, 256, 0, stream>>>(Wih1, W1p, 2048, 0, 1);
  conv_w<<<4096, 256, 0, stream>>>(Whh1, W1p, 2048, 1024, 1);
  conv_w<<<1024, 256, 0, stream>>>(Wlin, Wlinp, 1024, 0, 0);
  bias_k<<<16, 256, 0, stream>>>(bih0, bhh0, bih1, bhh1, Bx0, B1);

  // x0_proj = zn @ W_ih0p^T + (b_ih0 + b_hh0)   (constant over steps)
  gemm_k<0,0><<<dim3(32,8), 256, 0, stream>>>(H0a, Wih0p, 1024, Bx0, X0p);

  u16* h0b[2] = {H0a, H0b};
  u16* h1b[2] = {H1a, H1b};

  // h0(1) <- h0(0): L0 alone (nothing to overlap with yet)
  fused_step<<<dim3(32,8), 256, 0, stream>>>(h0b[0], nullptr, Whh0p, W1p, X0p, B1,
                                             C0, C1, h0b[1], nullptr, nullptr, 1);
  // steps t=0..30: L1(t) uses h0(t+1); concurrently L0 computes h0(t+2)
  for (int t = 0; t < 31; ++t){
    fused_step<<<dim3(32,16), 256, 0, stream>>>(
        h0b[(t+1)&1], h1b[t&1], Whh0p, W1p, X0p, B1,
        C0, C1, h0b[t&1], h1b[(t+1)&1], Feats + (size_t)t*1024, 0);
  }
  // final L1(31): uses h0(32)=h0b[0], h1 state h1b[1]
  fused_step<<<dim3(32,8), 256, 0, stream>>>(h0b[0], h1b[1], Whh0p, W1p, X0p, B1,
                                             C0, C1, nullptr, h1b[0], Feats + (size_t)31*1024, 2);

  // out = feats @ W_lin^T + b_lin  (XCD-chunked swizzle for A-tile L2 reuse)
  gemm_k<3,1><<<dim3(8,256), 256, 0, stream>>>(Feats, Wlinp, 1024, blin, out);
}